// Round 1
// baseline (439.954 us; speedup 1.0000x reference)
//
#include <hip/hip_runtime.h>
#include <stdint.h>

#define M_TOK 8192
#define N_OUT 4096
#define K_IN  4096

#define BM 128
#define BN 128
#define BK 64

typedef __attribute__((ext_vector_type(8))) short bf16x8;
typedef __attribute__((ext_vector_type(4))) float f32x4;
typedef __attribute__((ext_vector_type(4))) unsigned short u16x4;

static __device__ __forceinline__ unsigned short f2bf(float f) {
  // round-to-nearest-even f32 -> bf16 (inputs are finite, no NaN handling)
  uint32_t u = __builtin_bit_cast(uint32_t, f);
  u += 0x7fffu + ((u >> 16) & 1u);
  return (unsigned short)(u >> 16);
}

// ---------------------------------------------------------------------------
// Pass 1: convert x (f32) and weight_q (i32) into bf16 rows in workspace.
// A = x   as bf16 [M][K] row-major
// B = wq  as bf16 [N][K] row-major (B^T-style GEMM operand)
// ---------------------------------------------------------------------------
__global__ void convert_kernel(const float* __restrict__ x,
                               const int* __restrict__ wq,
                               unsigned short* __restrict__ A,
                               unsigned short* __restrict__ B) {
  const int nx4 = (M_TOK * K_IN) / 4;   // 8388608
  const int nw4 = (N_OUT * K_IN) / 4;   // 4194304
  const int total = nx4 + nw4;
  for (int i = blockIdx.x * blockDim.x + threadIdx.x; i < total;
       i += gridDim.x * blockDim.x) {
    if (i < nx4) {
      float4 f = reinterpret_cast<const float4*>(x)[i];
      u16x4 r;
      r.x = f2bf(f.x); r.y = f2bf(f.y); r.z = f2bf(f.z); r.w = f2bf(f.w);
      reinterpret_cast<u16x4*>(A)[i] = r;
    } else {
      int j = i - nx4;
      int4 v = reinterpret_cast<const int4*>(wq)[j];
      u16x4 r;
      r.x = f2bf((float)v.x); r.y = f2bf((float)v.y);
      r.z = f2bf((float)v.z); r.w = f2bf((float)v.w);
      reinterpret_cast<u16x4*>(B)[j] = r;
    }
  }
}

// ---------------------------------------------------------------------------
// Pass 2: bf16 MFMA GEMM, m97 structure (128x128 tile, BK=64, 4 waves,
// global_load_lds width 16, 16x16x32 MFMA, fused scale+bias epilogue).
// ---------------------------------------------------------------------------
#define GLOAD_LDS16(gptr, lptr)                                               \
  __builtin_amdgcn_global_load_lds(                                           \
      (const __attribute__((address_space(1))) void*)(gptr),                  \
      (__attribute__((address_space(3))) void*)(lptr), 16, 0, 0)

__global__ __launch_bounds__(256) void gemm_bf16(
    const unsigned short* __restrict__ A,   // [M][K] bf16
    const unsigned short* __restrict__ B,   // [N][K] bf16
    const float* __restrict__ scales,       // [N]
    const float* __restrict__ bias,         // [N]
    float* __restrict__ out) {              // [M][N] f32
  __shared__ unsigned short As[BM * BK];    // 16 KiB
  __shared__ unsigned short Bs[BN * BK];    // 16 KiB

  // XCD-aware bijective swizzle (gridDim.x = 2048, divisible by 8)
  int bid = blockIdx.x;
  int cpx = gridDim.x >> 3;
  int swz = (bid & 7) * cpx + (bid >> 3);
  int bx = swz & 31;        // N tile (N/BN = 32)
  int by = swz >> 5;        // M tile (M/BM = 64)

  int tid = threadIdx.x;
  int lane = tid & 63;
  int wid = tid >> 6;       // 0..3
  int wm = wid >> 1;        // wave row (2)
  int wn = wid & 1;         // wave col (2)

  // staging coords: wave w, issue i covers LDS elems [w*2048 + i*512, +512),
  // lane l supplies 8 bf16 at elem offset l*8. row = off/64, col = off%64.
  int st_row = wid * 32 + (lane >> 3);      // + i*8
  int st_col = (lane & 7) * 8;

  const unsigned short* Ab = A + (size_t)(by * BM) * K_IN;
  const unsigned short* Bb = B + (size_t)(bx * BN) * K_IN;

  f32x4 acc[4][4] = {};

  for (int k0 = 0; k0 < K_IN; k0 += BK) {
#pragma unroll
    for (int i = 0; i < 4; ++i) {
      int r = st_row + i * 8;
      GLOAD_LDS16(Ab + (size_t)r * K_IN + k0 + st_col, &As[wid * 2048 + i * 512]);
      GLOAD_LDS16(Bb + (size_t)r * K_IN + k0 + st_col, &Bs[wid * 2048 + i * 512]);
    }
    __syncthreads();   // compiler emits vmcnt(0) drain before barrier

#pragma unroll
    for (int kk = 0; kk < 2; ++kk) {
      int colk = kk * 32 + (lane >> 4) * 8;
      bf16x8 a[4], b[4];
#pragma unroll
      for (int m = 0; m < 4; ++m) {
        int row = wm * 64 + m * 16 + (lane & 15);
        a[m] = *reinterpret_cast<const bf16x8*>(&As[row * BK + colk]);
      }
#pragma unroll
      for (int n = 0; n < 4; ++n) {
        int row = wn * 64 + n * 16 + (lane & 15);
        b[n] = *reinterpret_cast<const bf16x8*>(&Bs[row * BK + colk]);
      }
#pragma unroll
      for (int m = 0; m < 4; ++m)
#pragma unroll
        for (int n = 0; n < 4; ++n)
          acc[m][n] =
              __builtin_amdgcn_mfma_f32_16x16x32_bf16(a[m], b[n], acc[m][n], 0, 0, 0);
    }
    __syncthreads();
  }

  // epilogue: out[row][col] = acc * scales[col] + bias[col]
  // C/D layout (m89-verified): col = lane&15, row = (lane>>4)*4 + reg
#pragma unroll
  for (int n = 0; n < 4; ++n) {
    int col = bx * BN + wn * 64 + n * 16 + (lane & 15);
    float s = scales[col];
    float bv = bias[col];
#pragma unroll
    for (int m = 0; m < 4; ++m) {
      int row0 = by * BM + wm * 64 + m * 16 + (lane >> 4) * 4;
#pragma unroll
      for (int r = 0; r < 4; ++r) {
        out[(size_t)(row0 + r) * N_OUT + col] = acc[m][n][r] * s + bv;
      }
    }
  }
}

// ---------------------------------------------------------------------------
// Fallback (only if ws_size too small): simple fp32 LDS-tiled GEMM. Correct
// but slow; safety net so we never fail on workspace size.
// ---------------------------------------------------------------------------
__global__ void fallback_gemm(const float* __restrict__ x,
                              const int* __restrict__ wq,
                              const float* __restrict__ scales,
                              const float* __restrict__ bias,
                              float* __restrict__ out) {
  __shared__ float xs[64][33];
  __shared__ float ws_[64][33];
  int tx = threadIdx.x & 15;
  int ty = threadIdx.x >> 4;
  int brow = blockIdx.y * 64, bcol = blockIdx.x * 64;
  float acc[4][4] = {};
  for (int k0 = 0; k0 < K_IN; k0 += 32) {
    for (int i = threadIdx.x; i < 64 * 32; i += 256) {
      int r = i >> 5, c = i & 31;
      xs[r][c] = x[(size_t)(brow + r) * K_IN + k0 + c];
      ws_[r][c] = (float)wq[(size_t)(bcol + r) * K_IN + k0 + c];
    }
    __syncthreads();
#pragma unroll 8
    for (int k = 0; k < 32; ++k) {
      float xv[4], wv[4];
#pragma unroll
      for (int i = 0; i < 4; ++i) xv[i] = xs[ty * 4 + i][k];
#pragma unroll
      for (int j = 0; j < 4; ++j) wv[j] = ws_[tx * 4 + j][k];
#pragma unroll
      for (int i = 0; i < 4; ++i)
#pragma unroll
        for (int j = 0; j < 4; ++j) acc[i][j] += xv[i] * wv[j];
    }
    __syncthreads();
  }
#pragma unroll
  for (int i = 0; i < 4; ++i)
#pragma unroll
    for (int j = 0; j < 4; ++j) {
      int o = bcol + tx * 4 + j;
      out[(size_t)(brow + ty * 4 + i) * N_OUT + o] = acc[i][j] * scales[o] + bias[o];
    }
}

extern "C" void kernel_launch(void* const* d_in, const int* in_sizes, int n_in,
                              void* d_out, int out_size, void* d_ws, size_t ws_size,
                              hipStream_t stream) {
  const float* x = (const float*)d_in[0];
  const int* wq = (const int*)d_in[1];
  const float* scales = (const float*)d_in[2];
  const float* bias = (const float*)d_in[3];
  float* out = (float*)d_out;

  const size_t needA = (size_t)M_TOK * K_IN * 2;   // 64 MiB
  const size_t needB = (size_t)N_OUT * K_IN * 2;   // 32 MiB

  if (ws_size >= needA + needB) {
    unsigned short* A = (unsigned short*)d_ws;
    unsigned short* B = (unsigned short*)((char*)d_ws + needA);
    convert_kernel<<<2048, 256, 0, stream>>>(x, wq, A, B);
    gemm_bf16<<<(M_TOK / BM) * (N_OUT / BN), 256, 0, stream>>>(A, B, scales, bias, out);
  } else {
    dim3 grid(N_OUT / 64, M_TOK / 64);
    fallback_gemm<<<grid, 256, 0, stream>>>(x, wq, scales, bias, out);
  }
}

// Round 2
// 277.933 us; speedup vs baseline: 1.5830x; 1.5830x over previous
//
#include <hip/hip_runtime.h>
#include <stdint.h>

#define M_TOK 8192
#define N_OUT 4096
#define K_IN  4096

#define BM 256
#define BN 256
#define BK 64
#define NT (K_IN / BK)   // 64 K-tiles
#define NIT (NT / 2)     // 32 iterations, 2 K-tiles each

typedef __attribute__((ext_vector_type(8))) short bf16x8;
typedef __attribute__((ext_vector_type(4))) float f32x4;
typedef __attribute__((ext_vector_type(4))) unsigned short u16x4;

static __device__ __forceinline__ unsigned short f2bf(float f) {
  uint32_t u = __builtin_bit_cast(uint32_t, f);
  u += 0x7fffu + ((u >> 16) & 1u);
  return (unsigned short)(u >> 16);
}

// ---------------------------------------------------------------------------
// Pass 1: convert x (f32) and weight_q (i32) into bf16 in workspace.
// A = x as bf16 [M][K]; B = wq as bf16 [N][K] (both row-major along K).
// ---------------------------------------------------------------------------
__global__ void convert_kernel(const float* __restrict__ x,
                               const int* __restrict__ wq,
                               unsigned short* __restrict__ A,
                               unsigned short* __restrict__ B) {
  const int nx4 = (M_TOK * K_IN) / 4;
  const int nw4 = (N_OUT * K_IN) / 4;
  const int total = nx4 + nw4;
  for (int i = blockIdx.x * blockDim.x + threadIdx.x; i < total;
       i += gridDim.x * blockDim.x) {
    if (i < nx4) {
      float4 f = reinterpret_cast<const float4*>(x)[i];
      u16x4 r;
      r.x = f2bf(f.x); r.y = f2bf(f.y); r.z = f2bf(f.z); r.w = f2bf(f.w);
      reinterpret_cast<u16x4*>(A)[i] = r;
    } else {
      int j = i - nx4;
      int4 v = reinterpret_cast<const int4*>(wq)[j];
      u16x4 r;
      r.x = f2bf((float)v.x); r.y = f2bf((float)v.y);
      r.z = f2bf((float)v.z); r.w = f2bf((float)v.w);
      reinterpret_cast<u16x4*>(B)[j] = r;
    }
  }
}

// ---------------------------------------------------------------------------
// Pass 2: 256x256 8-phase bf16 MFMA GEMM (T1+T2+T3+T4+T5), fused scale+bias.
// LDS layout (128 KiB):
//   A(buf,h) = buf*65536 + h*16384          (128 rows x 64 bf16 per half)
//   B(buf,h) = buf*65536 + 32768 + h*16384
// Swizzle: within a row (128 B = 8 slots of 16 B), phys_slot = log_slot ^ (row&7).
// Staged with linear LDS dest + inverse-swizzled per-lane GLOBAL source.
// ---------------------------------------------------------------------------
#define GLOAD_LDS16(gptr, lptr)                                               \
  __builtin_amdgcn_global_load_lds(                                           \
      (const __attribute__((address_space(1))) void*)(gptr),                  \
      (__attribute__((address_space(3))) void*)(lptr), 16, 0, 0)

#define WAITCNT(s) asm volatile("s_waitcnt " s ::: "memory")

// fragment reads (swizzled). row&7 == lane&7 for all fragment rows.
#define LDSA(buf, mh, fm, kk)                                                 \
  (*reinterpret_cast<const bf16x8*>(                                          \
      lds + (buf)*65536 + (mh)*16384 + aRow + (fm)*2048 +                     \
      (((((kk)*4) | sBase) ^ sXor) << 4)))
#define LDSB(buf, nh, fn, kk)                                                 \
  (*reinterpret_cast<const bf16x8*>(                                          \
      lds + (buf)*65536 + 32768 + (nh)*16384 + bRow + (fn)*2048 +             \
      (((((kk)*4) | sBase) ^ sXor) << 4)))

// stage one 128x64 half-tile: 2 x global_load_lds per wave (linear dest)
#define STAGE_A(buf, h, kt)                                                   \
  do {                                                                        \
    const unsigned short* _s = stA + (size_t)(h) * 128 * K_IN + (kt) * BK;    \
    GLOAD_LDS16(_s, lds + (buf)*65536 + (h)*16384 + ldsW0);                   \
    GLOAD_LDS16(_s + (size_t)64 * K_IN,                                       \
                lds + (buf)*65536 + (h)*16384 + 8192 + ldsW0);                \
  } while (0)
#define STAGE_B(buf, h, kt)                                                   \
  do {                                                                        \
    const unsigned short* _s = stB + (size_t)(h) * 128 * K_IN + (kt) * BK;    \
    GLOAD_LDS16(_s, lds + (buf)*65536 + 32768 + (h)*16384 + ldsW0);           \
    GLOAD_LDS16(_s + (size_t)64 * K_IN,                                       \
                lds + (buf)*65536 + 32768 + (h)*16384 + 8192 + ldsW0);        \
  } while (0)

#define MFMA16(mh, nh, BR)                                                    \
  do {                                                                        \
    _Pragma("unroll") for (int fm = 0; fm < 4; ++fm)                          \
    _Pragma("unroll") for (int fn = 0; fn < 2; ++fn) {                        \
      acc[mh][nh][fm][fn] = __builtin_amdgcn_mfma_f32_16x16x32_bf16(          \
          aR[fm][0], BR[fn][0], acc[mh][nh][fm][fn], 0, 0, 0);                \
      acc[mh][nh][fm][fn] = __builtin_amdgcn_mfma_f32_16x16x32_bf16(          \
          aR[fm][1], BR[fn][1], acc[mh][nh][fm][fn], 0, 0, 0);                \
    }                                                                         \
  } while (0)

#define PH_MID()                                                              \
  __builtin_amdgcn_s_barrier();                                               \
  WAITCNT("lgkmcnt(0)");                                                      \
  __builtin_amdgcn_sched_barrier(0);                                          \
  __builtin_amdgcn_s_setprio(1)

#define PH_END()                                                              \
  __builtin_amdgcn_s_setprio(0);                                              \
  __builtin_amdgcn_s_barrier();                                               \
  __builtin_amdgcn_sched_barrier(0)

#define PH_END_VM()                                                           \
  __builtin_amdgcn_s_setprio(0);                                              \
  WAITCNT("vmcnt(6)");                                                        \
  __builtin_amdgcn_sched_barrier(0);                                          \
  __builtin_amdgcn_s_barrier();                                               \
  __builtin_amdgcn_sched_barrier(0)

__global__ __launch_bounds__(512, 2) void gemm_8ph(
    const unsigned short* __restrict__ A,   // [M][K] bf16
    const unsigned short* __restrict__ B,   // [N][K] bf16
    const float* __restrict__ scales,       // [N]
    const float* __restrict__ bias,         // [N]
    float* __restrict__ out) {              // [M][N] f32
  __shared__ __align__(1024) char lds[131072];

  // XCD-aware bijective swizzle (512 blocks, 512 % 8 == 0)
  int bid = blockIdx.x;
  int swz = (bid & 7) * (512 / 8) + (bid >> 3);
  int bx = swz & 15;   // N tiles: 4096/256 = 16
  int by = swz >> 4;   // M tiles: 8192/256 = 32

  int tid = threadIdx.x;
  int lane = tid & 63;
  int wid = tid >> 6;   // 0..7
  int wm = wid >> 2;    // 0..1
  int wn = wid & 3;     // 0..3

  // per-lane read address pieces
  int aRow = (wm * 64 + (lane & 15)) * 128;   // bytes within A half
  int bRow = (wn * 32 + (lane & 15)) * 128;   // bytes within B half
  int sBase = lane >> 4;                      // logical slot low bits
  int sXor = lane & 7;                        // swizzle term (row&7)

  // per-lane staging sources (inverse-swizzled global addresses)
  const unsigned short* stA =
      A + (size_t)(by * BM + wid * 8 + (lane >> 3)) * K_IN +
      ((lane & 7) ^ (lane >> 3)) * 8;
  const unsigned short* stB =
      B + (size_t)(bx * BN + wid * 8 + (lane >> 3)) * K_IN +
      ((lane & 7) ^ (lane >> 3)) * 8;
  int ldsW0 = wid * 1024;   // wave's linear LDS slice (instr0); instr1 = +8192

  f32x4 acc[2][2][4][2] = {};   // [mh][nh][fm][fn]
  bf16x8 aR[4][2];              // current A m-half frags [fm][kk]
  bf16x8 bR0[2][2], bR1[2][2];  // B n-half frags [fn][kk]

  // ---- prologue: stage tile0 (buf0) + 3 halves of tile1 (buf1) ----
  STAGE_A(0, 0, 0); STAGE_A(0, 1, 0); STAGE_B(0, 0, 0); STAGE_B(0, 1, 0);
  WAITCNT("vmcnt(4)");
  STAGE_A(1, 0, 1); STAGE_B(1, 0, 1); STAGE_B(1, 1, 1);
  WAITCNT("vmcnt(6)");   // tile0 fully resident
  __builtin_amdgcn_s_barrier();
  __builtin_amdgcn_sched_barrier(0);

#pragma unroll 1
  for (int it = 0; it < NIT; ++it) {
    int kt1 = 2 * it + 1;            // tile t+1 (always < NT)
    int kt2 = (2 * it + 2) & (NT - 1);
    int kt3 = (2 * it + 3) & (NT - 1);

    // ---- P1: tile t, quad (m0,n0); stage t+1 A-h1 -> buf1 ----
#pragma unroll
    for (int fm = 0; fm < 4; ++fm) { aR[fm][0] = LDSA(0, 0, fm, 0); aR[fm][1] = LDSA(0, 0, fm, 1); }
#pragma unroll
    for (int fn = 0; fn < 2; ++fn) { bR0[fn][0] = LDSB(0, 0, fn, 0); bR0[fn][1] = LDSB(0, 0, fn, 1); }
    STAGE_A(1, 1, kt1);
    WAITCNT("lgkmcnt(8)");
    PH_MID();
    MFMA16(0, 0, bR0);
    PH_END();

    // ---- P2: tile t, quad (m0,n1); stage t+2 A-h0 -> buf0 ----
#pragma unroll
    for (int fn = 0; fn < 2; ++fn) { bR1[fn][0] = LDSB(0, 1, fn, 0); bR1[fn][1] = LDSB(0, 1, fn, 1); }
    STAGE_A(0, 0, kt2);
    PH_MID();
    MFMA16(0, 1, bR1);
    PH_END();

    // ---- P3: tile t, quad (m1,n1); stage t+2 B-h0 -> buf0 ----
#pragma unroll
    for (int fm = 0; fm < 4; ++fm) { aR[fm][0] = LDSA(0, 1, fm, 0); aR[fm][1] = LDSA(0, 1, fm, 1); }
    STAGE_B(0, 0, kt2);
    PH_MID();
    MFMA16(1, 1, bR1);
    PH_END();

    // ---- P4: tile t, quad (m1,n0); stage t+2 B-h1 -> buf0; vmcnt(6) ----
    STAGE_B(0, 1, kt2);
    PH_MID();
    MFMA16(1, 0, bR0);
    PH_END_VM();

    // ---- P5: tile t+1, quad (m0,n0); stage t+2 A-h1 -> buf0 ----
#pragma unroll
    for (int fm = 0; fm < 4; ++fm) { aR[fm][0] = LDSA(1, 0, fm, 0); aR[fm][1] = LDSA(1, 0, fm, 1); }
#pragma unroll
    for (int fn = 0; fn < 2; ++fn) { bR0[fn][0] = LDSB(1, 0, fn, 0); bR0[fn][1] = LDSB(1, 0, fn, 1); }
    STAGE_A(0, 1, kt2);
    WAITCNT("lgkmcnt(8)");
    PH_MID();
    MFMA16(0, 0, bR0);
    PH_END();

    // ---- P6: tile t+1, quad (m0,n1); stage t+3 A-h0 -> buf1 ----
#pragma unroll
    for (int fn = 0; fn < 2; ++fn) { bR1[fn][0] = LDSB(1, 1, fn, 0); bR1[fn][1] = LDSB(1, 1, fn, 1); }
    STAGE_A(1, 0, kt3);
    PH_MID();
    MFMA16(0, 1, bR1);
    PH_END();

    // ---- P7: tile t+1, quad (m1,n1); stage t+3 B-h0 -> buf1 ----
#pragma unroll
    for (int fm = 0; fm < 4; ++fm) { aR[fm][0] = LDSA(1, 1, fm, 0); aR[fm][1] = LDSA(1, 1, fm, 1); }
    STAGE_B(1, 0, kt3);
    PH_MID();
    MFMA16(1, 1, bR1);
    PH_END();

    // ---- P8: tile t+1, quad (m1,n0); stage t+3 B-h1 -> buf1; vmcnt(6) ----
    STAGE_B(1, 1, kt3);
    PH_MID();
    MFMA16(1, 0, bR0);
    PH_END_VM();
  }

  // ---- epilogue: out = acc*scale + bias; C/D: col=lane&15, row=(lane>>4)*4+reg
#pragma unroll
  for (int nh = 0; nh < 2; ++nh)
#pragma unroll
    for (int fn = 0; fn < 2; ++fn) {
      int col = bx * BN + nh * 128 + wn * 32 + fn * 16 + (lane & 15);
      float s = scales[col];
      float bv = bias[col];
#pragma unroll
      for (int mh = 0; mh < 2; ++mh)
#pragma unroll
        for (int fm = 0; fm < 4; ++fm) {
          int row0 = by * BM + mh * 128 + wm * 64 + fm * 16 + (lane >> 4) * 4;
          f32x4 v = acc[mh][nh][fm][fn];
#pragma unroll
          for (int r = 0; r < 4; ++r)
            out[(size_t)(row0 + r) * N_OUT + col] = v[r] * s + bv;
        }
    }
}

// ---------------------------------------------------------------------------
// Fallback (tiny ws): simple fp32 LDS-tiled GEMM (correct, slow).
// ---------------------------------------------------------------------------
__global__ void fallback_gemm(const float* __restrict__ x,
                              const int* __restrict__ wq,
                              const float* __restrict__ scales,
                              const float* __restrict__ bias,
                              float* __restrict__ out) {
  __shared__ float xs[64][33];
  __shared__ float ws_[64][33];
  int tx = threadIdx.x & 15;
  int ty = threadIdx.x >> 4;
  int brow = blockIdx.y * 64, bcol = blockIdx.x * 64;
  float acc[4][4] = {};
  for (int k0 = 0; k0 < K_IN; k0 += 32) {
    for (int i = threadIdx.x; i < 64 * 32; i += 256) {
      int r = i >> 5, c = i & 31;
      xs[r][c] = x[(size_t)(brow + r) * K_IN + k0 + c];
      ws_[r][c] = (float)wq[(size_t)(bcol + r) * K_IN + k0 + c];
    }
    __syncthreads();
#pragma unroll 8
    for (int k = 0; k < 32; ++k) {
      float xv[4], wv[4];
#pragma unroll
      for (int i = 0; i < 4; ++i) xv[i] = xs[ty * 4 + i][k];
#pragma unroll
      for (int j = 0; j < 4; ++j) wv[j] = ws_[tx * 4 + j][k];
#pragma unroll
      for (int i = 0; i < 4; ++i)
#pragma unroll
        for (int j = 0; j < 4; ++j) acc[i][j] += xv[i] * wv[j];
    }
    __syncthreads();
  }
#pragma unroll
  for (int i = 0; i < 4; ++i)
#pragma unroll
    for (int j = 0; j < 4; ++j) {
      int o = bcol + tx * 4 + j;
      out[(size_t)(brow + ty * 4 + i) * N_OUT + o] = acc[i][j] * scales[o] + bias[o];
    }
}

extern "C" void kernel_launch(void* const* d_in, const int* in_sizes, int n_in,
                              void* d_out, int out_size, void* d_ws, size_t ws_size,
                              hipStream_t stream) {
  const float* x = (const float*)d_in[0];
  const int* wq = (const int*)d_in[1];
  const float* scales = (const float*)d_in[2];
  const float* bias = (const float*)d_in[3];
  float* out = (float*)d_out;

  const size_t needA = (size_t)M_TOK * K_IN * 2;   // 64 MiB
  const size_t needB = (size_t)N_OUT * K_IN * 2;   // 32 MiB

  if (ws_size >= needA + needB) {
    unsigned short* A = (unsigned short*)d_ws;
    unsigned short* B = (unsigned short*)((char*)d_ws + needA);
    convert_kernel<<<2048, 256, 0, stream>>>(x, wq, A, B);
    gemm_8ph<<<(M_TOK / BM) * (N_OUT / BN), 512, 0, stream>>>(A, B, scales, bias, out);
  } else {
    dim3 grid(N_OUT / 64, M_TOK / 64);
    fallback_gemm<<<grid, 256, 0, stream>>>(x, wq, scales, bias, out);
  }
}

// Round 3
// 187.578 us; speedup vs baseline: 2.3454x; 1.4817x over previous
//
#include <hip/hip_runtime.h>
#include <stdint.h>

#define M_TOK 8192
#define N_OUT 4096
#define K_IN  4096

#define BM 256
#define BN 256
#define BK 128                 // bytes == elements (i8)
#define NT (K_IN / BK)         // 32 K-tiles
#define NIT (NT / 2)           // 16 iterations, 2 K-tiles each

typedef __attribute__((ext_vector_type(4))) int i32x4;     // 16B frag / i32 acc quad

// ---------------------------------------------------------------------------
// Pass 1a: per-token symmetric quantization of x -> i8 + per-row scale.
// One wave per row. q = rint(x * 127/max|row|), s_row = max/127.
// ---------------------------------------------------------------------------
__global__ void quant_x_kernel(const float* __restrict__ x,
                               char* __restrict__ A8,
                               float* __restrict__ sx) {
  int row = blockIdx.x * 4 + (threadIdx.x >> 6);
  int lane = threadIdx.x & 63;
  const float* xr = x + (size_t)row * K_IN;

  float4 v[4][4];
  float mx = 0.f;
#pragma unroll
  for (int c = 0; c < 4; ++c) {
    int base = c * 1024 + lane * 16;
#pragma unroll
    for (int j = 0; j < 4; ++j) {
      v[c][j] = *reinterpret_cast<const float4*>(xr + base + j * 4);
      mx = fmaxf(mx, fmaxf(fmaxf(fabsf(v[c][j].x), fabsf(v[c][j].y)),
                           fmaxf(fabsf(v[c][j].z), fabsf(v[c][j].w))));
    }
  }
#pragma unroll
  for (int m = 32; m > 0; m >>= 1) mx = fmaxf(mx, __shfl_xor(mx, m));

  float inv = (mx > 0.f) ? (127.0f / mx) : 0.f;
  if (lane == 0) sx[row] = (mx > 0.f) ? (mx / 127.0f) : 1.0f;

#pragma unroll
  for (int c = 0; c < 4; ++c) {
    int qi[16];
#pragma unroll
    for (int j = 0; j < 4; ++j) {
      qi[j * 4 + 0] = __float2int_rn(v[c][j].x * inv);
      qi[j * 4 + 1] = __float2int_rn(v[c][j].y * inv);
      qi[j * 4 + 2] = __float2int_rn(v[c][j].z * inv);
      qi[j * 4 + 3] = __float2int_rn(v[c][j].w * inv);
    }
    int4 p;
    int* pp = (int*)&p;
#pragma unroll
    for (int w = 0; w < 4; ++w) {
      int a0 = min(127, max(-127, qi[w * 4 + 0])) & 0xff;
      int a1 = min(127, max(-127, qi[w * 4 + 1])) & 0xff;
      int a2 = min(127, max(-127, qi[w * 4 + 2])) & 0xff;
      int a3 = min(127, max(-127, qi[w * 4 + 3])) & 0xff;
      pp[w] = a0 | (a1 << 8) | (a2 << 16) | (a3 << 24);
    }
    *reinterpret_cast<int4*>(A8 + (size_t)row * K_IN + c * 1024 + lane * 16) = p;
  }
}

// ---------------------------------------------------------------------------
// Pass 1b: pack weight_q (i32 in [-128,127]) -> i8, exact.
// ---------------------------------------------------------------------------
__global__ void pack_w_kernel(const int* __restrict__ wq, char* __restrict__ B8) {
  const int total = (N_OUT * K_IN) / 16;   // 16 i8 per thread-unit
  for (int i = blockIdx.x * blockDim.x + threadIdx.x; i < total;
       i += gridDim.x * blockDim.x) {
    int4 p;
    int* pp = (int*)&p;
#pragma unroll
    for (int w = 0; w < 4; ++w) {
      int4 s = reinterpret_cast<const int4*>(wq)[i * 4 + w];
      pp[w] = (s.x & 0xff) | ((s.y & 0xff) << 8) | ((s.z & 0xff) << 16) |
              ((s.w & 0xff) << 24);
    }
    reinterpret_cast<int4*>(B8)[i] = p;
  }
}

// ---------------------------------------------------------------------------
// Pass 2: 256x256 8-phase i8 MFMA GEMM (byte-identical schedule to the
// verified bf16 round-2 kernel; mfma_i32_16x16x64_i8, BK=128 bytes).
// LDS 128 KiB: A(buf,h)=buf*65536+h*16384; B(buf,h)=+32768.
// Swizzle: 128-B rows = 8 slots of 16 B; phys_slot = log_slot ^ (row&7);
// staged with linear LDS dest + inverse-swizzled global source (rule #21).
// ---------------------------------------------------------------------------
#define GLOAD_LDS16(gptr, lptr)                                               \
  __builtin_amdgcn_global_load_lds(                                           \
      (const __attribute__((address_space(1))) void*)(gptr),                  \
      (__attribute__((address_space(3))) void*)(lptr), 16, 0, 0)

#define WAITCNT(s) asm volatile("s_waitcnt " s ::: "memory")

#define LDSA(buf, mh, fm, kk)                                                 \
  (*reinterpret_cast<const i32x4*>(                                           \
      lds + (buf)*65536 + (mh)*16384 + aRow + (fm)*2048 +                     \
      (((((kk)*4) | sBase) ^ sXor) << 4)))
#define LDSB(buf, nh, fn, kk)                                                 \
  (*reinterpret_cast<const i32x4*>(                                           \
      lds + (buf)*65536 + 32768 + (nh)*16384 + bRow + (fn)*2048 +             \
      (((((kk)*4) | sBase) ^ sXor) << 4)))

#define STAGE_A(buf, h, kt)                                                   \
  do {                                                                        \
    const char* _s = stA + (size_t)(h) * 128 * K_IN + (kt) * BK;              \
    GLOAD_LDS16(_s, lds + (buf)*65536 + (h)*16384 + ldsW0);                   \
    GLOAD_LDS16(_s + (size_t)64 * K_IN,                                       \
                lds + (buf)*65536 + (h)*16384 + 8192 + ldsW0);                \
  } while (0)
#define STAGE_B(buf, h, kt)                                                   \
  do {                                                                        \
    const char* _s = stB + (size_t)(h) * 128 * K_IN + (kt) * BK;              \
    GLOAD_LDS16(_s, lds + (buf)*65536 + 32768 + (h)*16384 + ldsW0);           \
    GLOAD_LDS16(_s + (size_t)64 * K_IN,                                       \
                lds + (buf)*65536 + 32768 + (h)*16384 + 8192 + ldsW0);        \
  } while (0)

#define MFMA16(mh, nh, BR)                                                    \
  do {                                                                        \
    _Pragma("unroll") for (int fm = 0; fm < 4; ++fm)                          \
    _Pragma("unroll") for (int fn = 0; fn < 2; ++fn) {                        \
      acc[mh][nh][fm][fn] = __builtin_amdgcn_mfma_i32_16x16x64_i8(            \
          aR[fm][0], BR[fn][0], acc[mh][nh][fm][fn], 0, 0, 0);                \
      acc[mh][nh][fm][fn] = __builtin_amdgcn_mfma_i32_16x16x64_i8(            \
          aR[fm][1], BR[fn][1], acc[mh][nh][fm][fn], 0, 0, 0);                \
    }                                                                         \
  } while (0)

#define PH_MID()                                                              \
  __builtin_amdgcn_s_barrier();                                               \
  WAITCNT("lgkmcnt(0)");                                                      \
  __builtin_amdgcn_sched_barrier(0);                                          \
  __builtin_amdgcn_s_setprio(1)

#define PH_END()                                                              \
  __builtin_amdgcn_s_setprio(0);                                              \
  __builtin_amdgcn_s_barrier();                                               \
  __builtin_amdgcn_sched_barrier(0)

#define PH_END_VM()                                                           \
  __builtin_amdgcn_s_setprio(0);                                              \
  WAITCNT("vmcnt(6)");                                                        \
  __builtin_amdgcn_sched_barrier(0);                                          \
  __builtin_amdgcn_s_barrier();                                               \
  __builtin_amdgcn_sched_barrier(0)

__global__ __launch_bounds__(512, 2) void gemm_8ph_i8(
    const char* __restrict__ A,        // [M][K] i8
    const char* __restrict__ B,        // [N][K] i8
    const float* __restrict__ sx,      // [M] per-row x scales
    const float* __restrict__ scales,  // [N]
    const float* __restrict__ bias,    // [N]
    float* __restrict__ out) {         // [M][N] f32
  __shared__ __align__(1024) char lds[131072];

  int bid = blockIdx.x;
  int swz = (bid & 7) * (512 / 8) + (bid >> 3);   // bijective, 512 % 8 == 0
  int bx = swz & 15;   // N tiles: 16
  int by = swz >> 4;   // M tiles: 32

  int tid = threadIdx.x;
  int lane = tid & 63;
  int wid = tid >> 6;
  int wm = wid >> 2;    // 0..1
  int wn = wid & 3;     // 0..3

  int aRow = (wm * 64 + (lane & 15)) * 128;   // bytes within A half
  int bRow = (wn * 32 + (lane & 15)) * 128;   // bytes within B half
  int sBase = lane >> 4;                      // 0..3
  int sXor = lane & 7;

  const char* stA = A + (size_t)(by * BM + wid * 8 + (lane >> 3)) * K_IN +
                    ((lane & 7) ^ (lane >> 3)) * 16;
  const char* stB = B + (size_t)(bx * BN + wid * 8 + (lane >> 3)) * K_IN +
                    ((lane & 7) ^ (lane >> 3)) * 16;
  int ldsW0 = wid * 1024;

  i32x4 acc[2][2][4][2] = {};   // [mh][nh][fm][fn], i32
  i32x4 aR[4][2];               // A frags [fm][kk]
  i32x4 bR0[2][2], bR1[2][2];   // B frags [fn][kk]

  // ---- prologue: tile0 (buf0) fully + 3 halves of tile1 (buf1) ----
  STAGE_A(0, 0, 0); STAGE_A(0, 1, 0); STAGE_B(0, 0, 0); STAGE_B(0, 1, 0);
  WAITCNT("vmcnt(4)");
  STAGE_A(1, 0, 1); STAGE_B(1, 0, 1); STAGE_B(1, 1, 1);
  WAITCNT("vmcnt(6)");
  __builtin_amdgcn_s_barrier();
  __builtin_amdgcn_sched_barrier(0);

#pragma unroll 1
  for (int it = 0; it < NIT; ++it) {
    int kt1 = 2 * it + 1;
    int kt2 = (2 * it + 2) & (NT - 1);
    int kt3 = (2 * it + 3) & (NT - 1);

    // P1: tile t (m0,n0); stage t+1 A-h1 -> buf1
#pragma unroll
    for (int fm = 0; fm < 4; ++fm) { aR[fm][0] = LDSA(0, 0, fm, 0); aR[fm][1] = LDSA(0, 0, fm, 1); }
#pragma unroll
    for (int fn = 0; fn < 2; ++fn) { bR0[fn][0] = LDSB(0, 0, fn, 0); bR0[fn][1] = LDSB(0, 0, fn, 1); }
    STAGE_A(1, 1, kt1);
    WAITCNT("lgkmcnt(8)");
    PH_MID();
    MFMA16(0, 0, bR0);
    PH_END();

    // P2: tile t (m0,n1); stage t+2 A-h0 -> buf0
#pragma unroll
    for (int fn = 0; fn < 2; ++fn) { bR1[fn][0] = LDSB(0, 1, fn, 0); bR1[fn][1] = LDSB(0, 1, fn, 1); }
    STAGE_A(0, 0, kt2);
    PH_MID();
    MFMA16(0, 1, bR1);
    PH_END();

    // P3: tile t (m1,n1); stage t+2 B-h0 -> buf0
#pragma unroll
    for (int fm = 0; fm < 4; ++fm) { aR[fm][0] = LDSA(0, 1, fm, 0); aR[fm][1] = LDSA(0, 1, fm, 1); }
    STAGE_B(0, 0, kt2);
    PH_MID();
    MFMA16(1, 1, bR1);
    PH_END();

    // P4: tile t (m1,n0); stage t+2 B-h1 -> buf0; vmcnt(6)
    STAGE_B(0, 1, kt2);
    PH_MID();
    MFMA16(1, 0, bR0);
    PH_END_VM();

    // P5: tile t+1 (m0,n0); stage t+2 A-h1 -> buf0
#pragma unroll
    for (int fm = 0; fm < 4; ++fm) { aR[fm][0] = LDSA(1, 0, fm, 0); aR[fm][1] = LDSA(1, 0, fm, 1); }
#pragma unroll
    for (int fn = 0; fn < 2; ++fn) { bR0[fn][0] = LDSB(1, 0, fn, 0); bR0[fn][1] = LDSB(1, 0, fn, 1); }
    STAGE_A(0, 1, kt2);
    WAITCNT("lgkmcnt(8)");
    PH_MID();
    MFMA16(0, 0, bR0);
    PH_END();

    // P6: tile t+1 (m0,n1); stage t+3 A-h0 -> buf1
#pragma unroll
    for (int fn = 0; fn < 2; ++fn) { bR1[fn][0] = LDSB(1, 1, fn, 0); bR1[fn][1] = LDSB(1, 1, fn, 1); }
    STAGE_A(1, 0, kt3);
    PH_MID();
    MFMA16(0, 1, bR1);
    PH_END();

    // P7: tile t+1 (m1,n1); stage t+3 B-h0 -> buf1
#pragma unroll
    for (int fm = 0; fm < 4; ++fm) { aR[fm][0] = LDSA(1, 1, fm, 0); aR[fm][1] = LDSA(1, 1, fm, 1); }
    STAGE_B(1, 0, kt3);
    PH_MID();
    MFMA16(1, 1, bR1);
    PH_END();

    // P8: tile t+1 (m1,n0); stage t+3 B-h1 -> buf1; vmcnt(6)
    STAGE_B(1, 1, kt3);
    PH_MID();
    MFMA16(1, 0, bR0);
    PH_END_VM();
  }

  // ---- epilogue: out = acc * (sx[row] * scales[col]) + bias[col] ----
  // C/D (shape-determined): col = lane&15, row = (lane>>4)*4 + reg
  float sxv[2][4][4];
#pragma unroll
  for (int mh = 0; mh < 2; ++mh)
#pragma unroll
    for (int fm = 0; fm < 4; ++fm) {
      int row0 = by * BM + mh * 128 + wm * 64 + fm * 16 + (lane >> 4) * 4;
#pragma unroll
      for (int r = 0; r < 4; ++r) sxv[mh][fm][r] = sx[row0 + r];
    }

#pragma unroll
  for (int nh = 0; nh < 2; ++nh)
#pragma unroll
    for (int fn = 0; fn < 2; ++fn) {
      int col = bx * BN + nh * 128 + wn * 32 + fn * 16 + (lane & 15);
      float so = scales[col];
      float bv = bias[col];
#pragma unroll
      for (int mh = 0; mh < 2; ++mh)
#pragma unroll
        for (int fm = 0; fm < 4; ++fm) {
          int row0 = by * BM + mh * 128 + wm * 64 + fm * 16 + (lane >> 4) * 4;
          i32x4 v = acc[mh][nh][fm][fn];
#pragma unroll
          for (int r = 0; r < 4; ++r)
            out[(size_t)(row0 + r) * N_OUT + col] =
                (float)v[r] * (sxv[mh][fm][r] * so) + bv;
        }
    }
}

// ---------------------------------------------------------------------------
// Fallback (tiny ws): simple fp32 LDS-tiled GEMM (correct, slow).
// ---------------------------------------------------------------------------
__global__ void fallback_gemm(const float* __restrict__ x,
                              const int* __restrict__ wq,
                              const float* __restrict__ scales,
                              const float* __restrict__ bias,
                              float* __restrict__ out) {
  __shared__ float xs[64][33];
  __shared__ float ws_[64][33];
  int tx = threadIdx.x & 15;
  int ty = threadIdx.x >> 4;
  int brow = blockIdx.y * 64, bcol = blockIdx.x * 64;
  float acc[4][4] = {};
  for (int k0 = 0; k0 < K_IN; k0 += 32) {
    for (int i = threadIdx.x; i < 64 * 32; i += 256) {
      int r = i >> 5, c = i & 31;
      xs[r][c] = x[(size_t)(brow + r) * K_IN + k0 + c];
      ws_[r][c] = (float)wq[(size_t)(bcol + r) * K_IN + k0 + c];
    }
    __syncthreads();
#pragma unroll 8
    for (int k = 0; k < 32; ++k) {
      float xv[4], wv[4];
#pragma unroll
      for (int i = 0; i < 4; ++i) xv[i] = xs[ty * 4 + i][k];
#pragma unroll
      for (int j = 0; j < 4; ++j) wv[j] = ws_[tx * 4 + j][k];
#pragma unroll
      for (int i = 0; i < 4; ++i)
#pragma unroll
        for (int j = 0; j < 4; ++j) acc[i][j] += xv[i] * wv[j];
    }
    __syncthreads();
  }
#pragma unroll
  for (int i = 0; i < 4; ++i)
#pragma unroll
    for (int j = 0; j < 4; ++j) {
      int o = bcol + tx * 4 + j;
      out[(size_t)(brow + ty * 4 + i) * N_OUT + o] = acc[i][j] * scales[o] + bias[o];
    }
}

extern "C" void kernel_launch(void* const* d_in, const int* in_sizes, int n_in,
                              void* d_out, int out_size, void* d_ws, size_t ws_size,
                              hipStream_t stream) {
  const float* x = (const float*)d_in[0];
  const int* wq = (const int*)d_in[1];
  const float* scales = (const float*)d_in[2];
  const float* bias = (const float*)d_in[3];
  float* out = (float*)d_out;

  const size_t offB = (size_t)M_TOK * K_IN;            // 32 MiB (A8)
  const size_t offS = offB + (size_t)N_OUT * K_IN;     // +16 MiB (B8)
  const size_t need = offS + (size_t)M_TOK * 4;        // +32 KiB (sx)

  if (ws_size >= need) {
    char* A8 = (char*)d_ws;
    char* B8 = (char*)d_ws + offB;
    float* sx = (float*)((char*)d_ws + offS);
    quant_x_kernel<<<M_TOK / 4, 256, 0, stream>>>(x, A8, sx);
    pack_w_kernel<<<2048, 256, 0, stream>>>(wq, B8);
    gemm_8ph_i8<<<(M_TOK / BM) * (N_OUT / BN), 512, 0, stream>>>(
        A8, B8, sx, scales, bias, out);
  } else {
    dim3 grid(N_OUT / 64, M_TOK / 64);
    fallback_gemm<<<grid, 256, 0, stream>>>(x, wq, scales, bias, out);
  }
}